// Round 4
// baseline (739.032 us; speedup 1.0000x reference)
//
#include <hip/hip_runtime.h>
#include <math.h>

#define NB 16    // batch
#define SS 256   // spatial size (H = W = 256)
#define DV 32    // channels
#define MM 12    // w-dim (j) modes kept
#define MK 24    // h-dim (iy) modes kept (0..11 and 244..255)
#define LL 4     // layers
#define TWO_PI_N 0.024543692606170259679f   // 2*pi/256
#define HSTR 257 // fused-kernel LDS row stride (floats): 257 % 32 = 1 -> 2-way max (free)
#define SEGOFF (DV * HSTR)                  // LDS offset of per-block seg-phase table

typedef float v2f __attribute__((ext_vector_type(2)));   // -> v_pk_fma_f32

// Workspace (floats):
//   h   : [NB][DV][SS][SS]            134 MB, in-place per layer
//   A   : [NB][SS(iy)][MM(ky)][DV][2] 12.6 MB  (row-DFT of h; iy-major = coalesced)
//   g   : [NB][SS(iy)][MM][DV][2]     12.6 MB  (per-row spectral coeffs; consumers
//                                              read it wave-uniform -> s_loads. R3
//                                              lesson: moving g to LDS converts free
//                                              s_loads into ds_read broadcasts, +60us)
//   twT : [SS][MM][2]                  24 KB   (cos,-sin) fwd-DFT; fused path rows 0..31
//   wT  : [LL][ci][co]                 16 KB   (transposed conv weights)
//   tw2 : [MM][SS][2]                  24 KB   (cos,+sin) inverse j-DFT
// F is no longer materialized: k_cmg keeps it in LDS (producer-side fusion).

// --------------------------------------------- setup: tables + weight^T
__global__ __launch_bounds__(256) void k_prep(const float* __restrict__ ws_w,
        float* __restrict__ twT, float* __restrict__ wT, float* __restrict__ tw2)
{
    int j = threadIdx.x;
    #pragma unroll
    for (int k = 0; k < MM; ++k) {
        float ang = TWO_PI_N * (float)((k * j) & 255);
        float s, c; sincosf(ang, &s, &c);
        twT[j * (MM * 2) + 2 * k]     = c;
        twT[j * (MM * 2) + 2 * k + 1] = -s;
        tw2[(k * SS + j) * 2]     = c;
        tw2[(k * SS + j) * 2 + 1] = s;
    }
    for (int idx = threadIdx.x; idx < LL * DV * DV; idx += 256) {
        int l = idx >> 10, rem = idx & 1023, co = rem >> 5, ci = rem & 31;
        wT[(l * DV + ci) * DV + co] = ws_w[(l * DV + co) * DV + ci];
    }
}

// ---------------------------------------------------------------------------
// Fused row-DFT epilogue (proven R2 form). Precondition: smem[c*HSTR+j] holds
// the row, segphase table at SEGOFF, sync done.
// ---------------------------------------------------------------------------
__device__ __forceinline__ void row_dft_from_lds(float* smem,
        const float* __restrict__ twT, float* __restrict__ A,
        int b, int iy, int tid)
{
    int c   = tid & 31;
    int seg = tid >> 5;          // 0..7
    int j0  = seg << 5;

    v2f arai[MM];
    #pragma unroll
    for (int k = 0; k < MM; ++k) arai[k] = (v2f)(0.f);

    const float* hp = smem + c * HSTR + j0;
    #pragma unroll 2
    for (int i = 0; i < 32; ++i) {
        float v = hp[i];
        const v2f* twj = (const v2f*)(twT + (size_t)i * (MM * 2));  // block-uniform -> s_load
        #pragma unroll
        for (int k = 0; k < MM; ++k)
            arai[k] += twj[k] * v;   // packed (cos,-sin) fma, sgpr-pair operand
    }

    // apply segment phase: arai[k] *= (pr, pi) from the LDS table
    const float* ph = smem + SEGOFF + seg * (MM * 2);
    #pragma unroll
    for (int k = 0; k < MM; ++k) {
        float pr = ph[2 * k], pi = ph[2 * k + 1];
        float re = arai[k].x * pr - arai[k].y * pi;
        float im = arai[k].x * pi + arai[k].y * pr;
        arai[k].x = re; arai[k].y = im;
    }

    __syncthreads();                       // hs/table reads done; reuse main as red
    v2f* red = (v2f*)smem;                 // [tid][13] v2f (proven: 0 conflicts)
    #pragma unroll
    for (int k = 0; k < MM; ++k) red[tid * 13 + k] = arai[k];
    __syncthreads();

    // 384 outputs (k,c): consecutive o -> consecutive float2 -> coalesced 3KB
    #pragma unroll
    for (int rep = 0; rep < 2; ++rep) {
        int o = tid + rep * 256;
        if (o < 384) {
            int k = o >> 5, cc = o & 31;
            v2f s = (v2f)(0.f);
            #pragma unroll
            for (int sg = 0; sg < 8; ++sg)
                s += red[(sg * 32 + cc) * 13 + k];
            size_t off = ((((size_t)(b * SS + iy)) * MM + k) * DV + cc) * 2;
            A[off]     = s.x;
            A[off + 1] = s.y;
        }
    }
}

// build the 8x12 seg-phase table into LDS (threads 0..95)
__device__ __forceinline__ void build_segphase(float* smem, int tid)
{
    if (tid < 8 * MM) {
        int s = tid / MM, k = tid - s * MM;
        float ang = TWO_PI_N * (float)(((k * s) << 5) & 255);
        float sn, cs; sincosf(ang, &sn, &cs);
        smem[SEGOFF + 2 * tid]     = cs;
        smem[SEGOFF + 2 * tid + 1] = -sn;
    }
}

// ------------------------------------------- lifting fused with row-DFT(l=0)
// grid = NB*SS (one row per block); 256 threads, 1 px/thread.
__global__ __launch_bounds__(256, 4) void k_liftdft(const float* __restrict__ x,
        const float* __restrict__ p_w, const float* __restrict__ p_b,
        float* __restrict__ h, const float* __restrict__ twT, float* __restrict__ A)
{
    __shared__ float smem[SEGOFF + 8 * MM * 2];      // 33.6 KB -> 4 blocks/CU
    int tid = threadIdx.x;
    int b  = blockIdx.x >> 8;
    int iy = blockIdx.x & 255;
    int j  = tid;

    build_segphase(smem, tid);

    float xv = x[((size_t)(b * SS + iy)) * SS + j];
    float gy = -1.f + 2.f * (float)iy * (1.f / 255.f);
    float gx = -1.f + 2.f * (float)j  * (1.f / 255.f);

    float* hb = h + ((size_t)b * DV * SS + iy) * SS + j;
    #pragma unroll
    for (int c = 0; c < DV; ++c) {
        float v = p_w[3*c] * xv + p_w[3*c+1] * gy + p_w[3*c+2] * gx + p_b[c];
        *(hb + (size_t)c * SS * SS) = v;
        smem[c * HSTR + j] = v;            // bank (c+j)%32: conflict-free
    }
    __syncthreads();
    row_dft_from_lds(smem, twT, A, b, iy, tid);
}

// ----------------- pointwise fused with row-DFT for the NEXT layer (R2-proven).
// h = relu(conv1x1(h) + invDFT(g)), then A = rowDFT(h) from LDS.
// g is read from GLOBAL with wave-uniform addresses -> s_loads (do not move to LDS).
__global__ __launch_bounds__(256, 4) void k_ptdft(float* __restrict__ h,
        const float* __restrict__ g, const float* __restrict__ wT,
        const float* __restrict__ ws_b, const float* __restrict__ tw2,
        const float* __restrict__ twT, float* __restrict__ A, int l)
{
    __shared__ float smem[SEGOFF + 8 * MM * 2];      // 33.6 KB -> 4 blocks/CU
    int tid = threadIdx.x;
    int b  = blockIdx.x >> 8;
    int iy = blockIdx.x & 255;
    int j  = tid;

    build_segphase(smem, tid);

    float* hb = h + ((size_t)b * DV * SS + iy) * SS + j;
    const float* wt  = wT + (size_t)l * DV * DV;     // [ci][co], uniform
    const float* wsb = ws_b + (size_t)l * DV;

    float acc[DV];
    #pragma unroll
    for (int co = 0; co < DV; ++co) acc[co] = wsb[co];

    #pragma unroll 4
    for (int ci = 0; ci < DV; ++ci) {
        float hv = *(hb + (size_t)ci * SS * SS);
        const float* wc = wt + ci * DV;              // 32 contiguous s_loads
        #pragma unroll
        for (int co = 0; co < DV; ++co) acc[co] += wc[co] * hv;
    }

    const float* gp = g + ((size_t)(b * SS + iy)) * (MM * DV * 2);  // uniform
    #pragma unroll 2
    for (int ky = 0; ky < MM; ++ky) {
        float2 t2 = *(const float2*)(tw2 + ((size_t)ky * SS + j) * 2);
        const float* Gk = gp + ky * (DV * 2);        // 64 contiguous s_loads
        #pragma unroll
        for (int co = 0; co < DV; ++co) {
            float gr = Gk[2 * co], gi = Gk[2 * co + 1];
            acc[co] += gr * t2.x - gi * t2.y;
        }
    }

    #pragma unroll
    for (int co = 0; co < DV; ++co) {
        float v = fmaxf(acc[co], 0.f);               // all fused layers relu
        *(hb + (size_t)co * SS * SS) = v;
        smem[co * HSTR + j] = v;                     // conflict-free
    }
    __syncthreads();
    row_dft_from_lds(smem, twT, A, b, iy, tid);
}

// ---------------------------------------------------------------------------
// k_cmg: iy-DFT of A + channel mix (ex-k_cm, all 24 modes in one block) with
// F kept in LDS, then inverse-iy DFT -> g (ex-k_inv1) in the same block.
// grid = NB*MM (one block per (b,ky)); 256 threads.
// Phase 1-3 arithmetic is op-for-op the R2 k_cm (per-mode chains identical);
// phase 4 is op-for-op the R2 k_inv1 -> bit-identical g.
// ---------------------------------------------------------------------------
__global__ __launch_bounds__(256) void k_cmg(const float* __restrict__ A,
        const float* __restrict__ w1r, const float* __restrict__ w1i,
        const float* __restrict__ w2r, const float* __restrict__ w2i,
        float* __restrict__ g, int l)
{
    __shared__ float red[4][DV][25][2];   // stride 50 words: 2-way max = free
    __shared__ float FinS[DV][25][2];
    __shared__ float FLDS[MK][DV][2];     // F in LDS; broadcast reads in phase 4
    int bk = blockIdx.x;                  // b*MM + ky
    int b  = bk / MM;
    int ky = bk - b * MM;
    int tid = threadIdx.x;
    int c = tid & 31, ch = tid >> 5;
    int iy0 = ch * 32;

    // ---- phase 1: Fin[m] = sum_iy A[b][iy][ky][c] * e^{-i 2pi f_m iy/256}
    const float2* Ap = (const float2*)(A) + ((size_t)(b * SS) * MM + ky) * DV + c;

    float fr[MK], fi[MK], pc[MK], ps[MK], sc[MK], ssn[MK];
    #pragma unroll
    for (int k = 0; k < MK; ++k) {
        int f = (k < MM) ? k : (232 + k);    // 244..255 for m >= 12
        float s, cc;
        sincosf(TWO_PI_N * (float)f, &s, &cc);
        sc[k] = cc; ssn[k] = s;
        sincosf(TWO_PI_N * (float)((f * iy0) & 255), &s, &cc);
        pc[k] = cc; ps[k] = s;
        fr[k] = fi[k] = 0.f;
    }
    #pragma unroll 2
    for (int i = 0; i < 32; ++i) {
        float2 a = Ap[(size_t)(iy0 + i) * (MM * DV)];
        #pragma unroll
        for (int k = 0; k < MK; ++k) {
            fr[k] += a.x * pc[k] + a.y * ps[k];   // A * e^{-i th}
            fi[k] += a.y * pc[k] - a.x * ps[k];
            float np = pc[k] * sc[k] - ps[k] * ssn[k];
            float nq = pc[k] * ssn[k] + ps[k] * sc[k];
            pc[k] = np; ps[k] = nq;
        }
    }
    #pragma unroll
    for (int k = 0; k < MK; ++k) {
        fr[k] += __shfl_xor(fr[k], 32, 64);
        fi[k] += __shfl_xor(fi[k], 32, 64);
    }
    int wv = tid >> 6;
    if ((tid & 63) < 32) {
        #pragma unroll
        for (int k = 0; k < MK; ++k) {
            red[wv][c][k][0] = fr[k];
            red[wv][c][k][1] = fi[k];
        }
    }
    __syncthreads();
    #pragma unroll
    for (int rep = 0; rep < 3; ++rep) {          // 768 = 3*256 outputs (cc,k2)
        int idx = rep * 256 + tid;
        int cc = idx & 31, k2 = idx >> 5;
        float sr = 0.f, si = 0.f;
        #pragma unroll
        for (int w = 0; w < 4; ++w) {
            sr += red[w][cc][k2][0];
            si += red[w][cc][k2][1];
        }
        FinS[cc][k2][0] = sr; FinS[cc][k2][1] = si;
    }
    __syncthreads();

    // ---- phase 3: channel mix -> F (pre-scaled) in LDS
    float scale = ((ky == 0) ? 1.0f : 2.0f) * (1.0f / 65536.0f);
    #pragma unroll
    for (int rep = 0; rep < 3; ++rep) {          // 768 = 3*256 outputs (o,m)
        int idx = rep * 256 + tid;
        int o = idx & 31, m = idx >> 5;
        const float* Wr; const float* Wi; int xm;
        if (m < MM) { Wr = w1r; Wi = w1i; xm = m; }
        else        { Wr = w2r; Wi = w2i; xm = m - MM; }
        float orr = 0.f, oii = 0.f;
        #pragma unroll 4
        for (int i = 0; i < DV; ++i) {
            float gr = FinS[i][m][0], gi = FinS[i][m][1];
            size_t wi = ((size_t)(l * DV + i) * DV + o) * (MM * MM) + xm * MM + ky;
            float wr = Wr[wi], wim = Wi[wi];
            orr += gr * wr - gi * wim;
            oii += gr * wim + gi * wr;
        }
        FLDS[m][o][0] = orr * scale;
        FLDS[m][o][1] = oii * scale;
    }
    __syncthreads();

    // ---- phase 4 (ex-k_inv1): thread = iy; g[b][iy][ky][co] for all co.
    // Same m-ascending accumulation order & expressions as k_inv1.
    int iy = tid;
    float twc[MK], tws[MK];
    #pragma unroll
    for (int m = 0; m < MK; ++m) {
        int f = (m < MM) ? m : (232 + m);
        float s, cc; sincosf(TWO_PI_N * (float)((f * iy) & 255), &s, &cc);
        twc[m] = cc; tws[m] = s;
    }
    float2 gacc[DV];
    #pragma unroll
    for (int co = 0; co < DV; ++co) { gacc[co].x = 0.f; gacc[co].y = 0.f; }
    for (int m = 0; m < MK; ++m) {
        float ic = twc[m], is = tws[m];
        #pragma unroll
        for (int co = 0; co < DV; ++co) {
            float2 fv = *(const float2*)&FLDS[m][co][0];   // uniform -> broadcast
            gacc[co].x += fv.x * ic - fv.y * is;
            gacc[co].y += fv.x * is + fv.y * ic;
        }
    }
    float* go = g + (((size_t)(b * SS + iy)) * MM + ky) * (DV * 2);
    #pragma unroll
    for (int co = 0; co < DV; ++co)
        *(float2*)(go + 2 * co) = gacc[co];
}

// ----------------- FINAL-layer pointwise (projection to out); R2-proven form.
// grid = NB*128; block = 2 rows x 2 j-halves, 2 px/thread; g via s_loads.
template<int FINAL>
__global__ __launch_bounds__(256, 4) void k_pt(float* __restrict__ h,
        const float* __restrict__ g, const float* __restrict__ wT,
        const float* __restrict__ ws_b, const float* __restrict__ tw2,
        const float* __restrict__ q_w, const float* __restrict__ q_b,
        float* __restrict__ out, int l)
{
    int tid = threadIdx.x;
    int lane = tid & 63;
    int w = __builtin_amdgcn_readfirstlane(tid >> 6);
    int b  = blockIdx.x >> 7;
    int iy = ((blockIdx.x & 127) << 1) + (w >> 1);
    int j0 = ((w & 1) << 7) + (lane << 1);

    float* hb = h + ((size_t)b * DV * SS + iy) * SS + j0;
    const float* wt  = wT + (size_t)l * DV * DV;     // [ci][co], uniform
    const float* wsb = ws_b + (size_t)l * DV;

    float2 acc[DV];
    #pragma unroll
    for (int co = 0; co < DV; ++co) {
        float bv = wsb[co];
        acc[co].x = bv; acc[co].y = bv;
    }

    #pragma unroll 4
    for (int ci = 0; ci < DV; ++ci) {
        float2 hv = *(const float2*)(hb + (size_t)ci * SS * SS);
        const float* wc = wt + ci * DV;              // 32 contiguous s_loads
        #pragma unroll
        for (int co = 0; co < DV; ++co) {
            float wv = wc[co];
            acc[co].x += wv * hv.x; acc[co].y += wv * hv.y;
        }
    }

    const float* gp = g + ((size_t)(b * SS + iy)) * (MM * DV * 2);  // uniform
    #pragma unroll 2
    for (int ky = 0; ky < MM; ++ky) {
        float4 t4 = *(const float4*)(tw2 + ((size_t)ky * SS + j0) * 2);
        const float* Gk = gp + ky * (DV * 2);        // 64 contiguous s_loads
        #pragma unroll
        for (int co = 0; co < DV; ++co) {
            float gr = Gk[2 * co], gi = Gk[2 * co + 1];
            acc[co].x += gr * t4.x - gi * t4.y;
            acc[co].y += gr * t4.z - gi * t4.w;
        }
    }

    if (FINAL) {
        float qb = q_b[0];
        float2 o2; o2.x = qb; o2.y = qb;
        #pragma unroll
        for (int co = 0; co < DV; ++co) {
            float qv = q_w[co];
            o2.x += qv * acc[co].x; o2.y += qv * acc[co].y;
        }
        *(float2*)(out + ((size_t)(b * SS + iy)) * SS + j0) = o2;
    } else {
        #pragma unroll
        for (int co = 0; co < DV; ++co) {
            float2 v;
            v.x = fmaxf(acc[co].x, 0.f); v.y = fmaxf(acc[co].y, 0.f);
            *(float2*)(hb + (size_t)co * SS * SS) = v;
        }
    }
}

extern "C" void kernel_launch(void* const* d_in, const int* in_sizes, int n_in,
                              void* d_out, int out_size, void* d_ws, size_t ws_size,
                              hipStream_t stream)
{
    const float* x    = (const float*)d_in[0];
    const float* p_w  = (const float*)d_in[1];
    const float* p_b  = (const float*)d_in[2];
    const float* ws_w = (const float*)d_in[3];
    const float* ws_b = (const float*)d_in[4];
    const float* w1r  = (const float*)d_in[5];
    const float* w1i  = (const float*)d_in[6];
    const float* w2r  = (const float*)d_in[7];
    const float* w2i  = (const float*)d_in[8];
    const float* q_w  = (const float*)d_in[9];
    const float* q_b  = (const float*)d_in[10];
    float* out = (float*)d_out;

    float* h   = (float*)d_ws;
    float* A   = h   + (size_t)NB * DV * SS * SS;
    float* g   = A   + (size_t)NB * SS * MM * DV * 2;
    float* twT = g   + (size_t)NB * SS * MM * DV * 2;
    float* wT  = twT + (size_t)SS * MM * 2;
    float* tw2 = wT  + (size_t)LL * DV * DV;

    dim3 blk(256);
    k_prep<<<1, blk, 0, stream>>>(ws_w, twT, wT, tw2);
    // lifting + row-DFT for layer 0's A, fused
    k_liftdft<<<NB * SS, blk, 0, stream>>>(x, p_w, p_b, h, twT, A);
    for (int l = 0; l < LL; ++l) {
        // iy-DFT + channel mix + inverse-iy DFT -> g, one kernel (F in LDS)
        k_cmg<<<NB * MM, blk, 0, stream>>>(A, w1r, w1i, w2r, w2i, g, l);
        if (l < LL - 1)
            k_ptdft<<<NB * SS, blk, 0, stream>>>(h, g, wT, ws_b, tw2, twT, A, l);
        else
            k_pt<1><<<NB * 128, blk, 0, stream>>>(h, g, wT, ws_b, tw2,
                                                  q_w, q_b, out, l);
    }
}

// Round 5
// 715.294 us; speedup vs baseline: 1.0332x; 1.0332x over previous
//
#include <hip/hip_runtime.h>
#include <math.h>

#define NB 16    // batch
#define SS 256   // spatial size (H = W = 256)
#define DV 32    // channels
#define MM 12    // w-dim (j) modes kept
#define MK 24    // h-dim (iy) modes kept (0..11 and 244..255)
#define LL 4     // layers
#define TWO_PI_N 0.024543692606170259679f   // 2*pi/256
#define HSTR 257 // LDS staging row stride: 257 % 32 = 1 -> max 2-way (free)
// Fused-kernel LDS map (floats). Staging holds 16 channels (half) at a time:
#define H16   (16 * HSTR)            // 4112: staging [16 c][257]
#define SEGO  H16                    // 384:  seg-phase [16 s][12 k][2]
#define REDO  (H16 + 16 * MM * 2)    // 4496: red [4 w][16 cc][13] v2f (pad 13)
#define LDSF  (REDO + 4 * 16 * 13 * 2)   // 6160 floats = 24.6 KB -> 6 blocks/CU

typedef float v2f __attribute__((ext_vector_type(2)));   // -> v_pk_fma_f32

// Workspace (floats):
//   h   : [NB][DV][SS][SS]            134 MB, in-place per layer
//   A   : [NB][SS(iy)][MM(ky)][DV][2] 12.6 MB  (row-DFT of h; iy-major = coalesced)
//   F   : [NB][ky:MM][m:MK][co:DV][2]  1.2 MB
//   g   : [NB][SS(iy)][MM][DV][2]     12.6 MB  (consumers read wave-uniform -> s_loads;
//                                              R3 lesson: never move g to LDS)
//   twT : [SS][MM][2]                  24 KB   (cos,-sin) fwd-DFT; fused path rows 0..15
//   wT  : [LL][ci][co]                 16 KB
//   tw2 : [MM][SS][2]                  24 KB
// R4 lesson: k_cm/k_inv1 stay separate (cmg fusion: 192 blocks + 144-VGPR
// recurrence + 768 ds-broadcasts = net -60us).

// --------------------------------------------- setup: tables + weight^T
__global__ __launch_bounds__(256) void k_prep(const float* __restrict__ ws_w,
        float* __restrict__ twT, float* __restrict__ wT, float* __restrict__ tw2)
{
    int j = threadIdx.x;
    #pragma unroll
    for (int k = 0; k < MM; ++k) {
        float ang = TWO_PI_N * (float)((k * j) & 255);
        float s, c; sincosf(ang, &s, &c);
        twT[j * (MM * 2) + 2 * k]     = c;
        twT[j * (MM * 2) + 2 * k + 1] = -s;
        tw2[(k * SS + j) * 2]     = c;
        tw2[(k * SS + j) * 2 + 1] = s;
    }
    for (int idx = threadIdx.x; idx < LL * DV * DV; idx += 256) {
        int l = idx >> 10, rem = idx & 1023, co = rem >> 5, ci = rem & 31;
        wT[(l * DV + ci) * DV + co] = ws_w[(l * DV + co) * DV + ci];
    }
}

// build 16-seg phase table: (cos,-sin)(2*pi*k*(16 s)/256); threads 0..191
__device__ __forceinline__ void build_segphase16(float* smem, int tid)
{
    if (tid < 16 * MM) {
        int s = tid / MM, k = tid - s * MM;
        float ang = TWO_PI_N * (float)(((k * s) << 4) & 255);
        float sn, cs; sincosf(ang, &sn, &cs);
        smem[SEGO + 2 * tid]     = cs;
        smem[SEGO + 2 * tid + 1] = -sn;
    }
}

// ---------------------------------------------------------------------------
// Row-DFT epilogue, two 16-channel passes (halves LDS vs R2 -> 6 blocks/CU).
//   A[k] = sum_s e^{-2pi i k (16s)/256} * sum_{i<16} h[16s+i] e^{-2pi i k i/256}
// Inner twiddles = twT rows 0..15, block-uniform -> s_loads (proven form).
// acc[] = this thread's 32 channel values for pixel (iy, j=tid).
// Staging read: addr = cc*257 + seg*16 + i -> 2-way max (free).
// Seg reduce: shfl_xor(16,32) intra-wave, then 4-wave LDS red (pad-13, no conflict).
// 4 barriers total (2 per half; half-1 staging shares half-0's finalize window).
// ---------------------------------------------------------------------------
__device__ __forceinline__ void row_dft_epilogue(float* smem,
        const float* __restrict__ twT, float* __restrict__ A,
        const float* acc, int b, int iy, int tid)
{
    int cc  = tid & 15;
    int seg = tid >> 4;          // 0..15
    int j   = tid;
    size_t abase = ((size_t)(b * SS + iy)) * MM;
    v2f* red = (v2f*)(smem + REDO);
    int w = tid >> 6;

    #pragma unroll
    for (int half = 0; half < 2; ++half) {
        #pragma unroll
        for (int c = 0; c < 16; ++c)
            smem[c * HSTR + j] = acc[half * 16 + c];
        __syncthreads();

        v2f arai[MM];
        #pragma unroll
        for (int k = 0; k < MM; ++k) arai[k] = (v2f)(0.f);
        const float* hp = smem + cc * HSTR + seg * 16;
        #pragma unroll 2
        for (int i = 0; i < 16; ++i) {
            float v = hp[i];
            const v2f* twj = (const v2f*)(twT + (size_t)i * (MM * 2)); // uniform
            #pragma unroll
            for (int k = 0; k < MM; ++k)
                arai[k] += twj[k] * v;       // packed (cos,-sin) fma
        }
        const float* ph = smem + SEGO + seg * (MM * 2);
        #pragma unroll
        for (int k = 0; k < MM; ++k) {
            float pr = ph[2 * k], pi = ph[2 * k + 1];
            float re = arai[k].x * pr - arai[k].y * pi;
            float im = arai[k].x * pi + arai[k].y * pr;
            arai[k].x = re; arai[k].y = im;
        }
        // reduce the 4 segs resident in this wave (lanes differ in tid bits 4-5)
        #pragma unroll
        for (int k = 0; k < MM; ++k) {
            arai[k].x += __shfl_xor(arai[k].x, 16, 64);
            arai[k].y += __shfl_xor(arai[k].y, 16, 64);
            arai[k].x += __shfl_xor(arai[k].x, 32, 64);
            arai[k].y += __shfl_xor(arai[k].y, 32, 64);
        }
        if ((tid & 48) == 0) {               // one writer lane per (w, cc)
            #pragma unroll
            for (int k = 0; k < MM; ++k)
                red[(w * 16 + cc) * 13 + k] = arai[k];
        }
        __syncthreads();
        if (tid < 192) {                     // finalize: k2 in [0,12), c2 in [0,16)
            int k2 = tid >> 4, c2 = tid & 15;
            v2f s = (v2f)(0.f);
            #pragma unroll
            for (int wv = 0; wv < 4; ++wv)
                s += red[(wv * 16 + c2) * 13 + k2];
            size_t off = ((abase + k2) * DV + half * 16 + c2) * 2;
            A[off]     = s.x;
            A[off + 1] = s.y;
        }
        // no extra barrier: half-1 staging writes only the h region (reads done
        // before the red barrier); red is re-written only after the next barrier.
    }
}

// ------------------------------------------- lifting fused with row-DFT(l=0)
// grid = NB*SS (one row per block); 256 threads, 1 px/thread.
__global__ __launch_bounds__(256, 4) void k_liftdft(const float* __restrict__ x,
        const float* __restrict__ p_w, const float* __restrict__ p_b,
        float* __restrict__ h, const float* __restrict__ twT, float* __restrict__ A)
{
    __shared__ float smem[LDSF];             // 24.6 KB -> 6 blocks/CU
    int tid = threadIdx.x;
    int b  = blockIdx.x >> 8;
    int iy = blockIdx.x & 255;
    int j  = tid;

    build_segphase16(smem, tid);

    float xv = x[((size_t)(b * SS + iy)) * SS + j];
    float gy = -1.f + 2.f * (float)iy * (1.f / 255.f);
    float gx = -1.f + 2.f * (float)j  * (1.f / 255.f);

    float* hb = h + ((size_t)b * DV * SS + iy) * SS + j;
    float hv[DV];
    #pragma unroll
    for (int c = 0; c < DV; ++c) {
        hv[c] = p_w[3*c] * xv + p_w[3*c+1] * gy + p_w[3*c+2] * gx + p_b[c];
        *(hb + (size_t)c * SS * SS) = hv[c];
    }
    row_dft_epilogue(smem, twT, A, hv, b, iy, tid);
}

// ----------------- pointwise fused with row-DFT for the NEXT layer.
// h = relu(conv1x1(h) + invDFT(g)), then A = rowDFT(h). grid = NB*SS.
// g via wave-uniform GLOBAL reads -> s_loads (R3 lesson: never LDS).
__global__ __launch_bounds__(256, 4) void k_ptdft(float* __restrict__ h,
        const float* __restrict__ g, const float* __restrict__ wT,
        const float* __restrict__ ws_b, const float* __restrict__ tw2,
        const float* __restrict__ twT, float* __restrict__ A, int l)
{
    __shared__ float smem[LDSF];             // 24.6 KB -> 6 blocks/CU
    int tid = threadIdx.x;
    int b  = blockIdx.x >> 8;
    int iy = blockIdx.x & 255;
    int j  = tid;

    build_segphase16(smem, tid);

    float* hb = h + ((size_t)b * DV * SS + iy) * SS + j;
    const float* wt  = wT + (size_t)l * DV * DV;     // [ci][co], uniform
    const float* wsb = ws_b + (size_t)l * DV;

    float acc[DV];
    #pragma unroll
    for (int co = 0; co < DV; ++co) acc[co] = wsb[co];

    #pragma unroll 4
    for (int ci = 0; ci < DV; ++ci) {
        float hv = *(hb + (size_t)ci * SS * SS);
        const float* wc = wt + ci * DV;              // 32 contiguous s_loads
        #pragma unroll
        for (int co = 0; co < DV; ++co) acc[co] += wc[co] * hv;
    }

    const float* gp = g + ((size_t)(b * SS + iy)) * (MM * DV * 2);  // uniform
    #pragma unroll 2
    for (int ky = 0; ky < MM; ++ky) {
        float2 t2 = *(const float2*)(tw2 + ((size_t)ky * SS + j) * 2);
        const float* Gk = gp + ky * (DV * 2);        // 64 contiguous s_loads
        #pragma unroll
        for (int co = 0; co < DV; ++co) {
            float gr = Gk[2 * co], gi = Gk[2 * co + 1];
            acc[co] += gr * t2.x - gi * t2.y;
        }
    }

    #pragma unroll
    for (int co = 0; co < DV; ++co) {
        acc[co] = fmaxf(acc[co], 0.f);               // all fused layers relu
        *(hb + (size_t)co * SS * SS) = acc[co];
    }
    row_dft_epilogue(smem, twT, A, acc, b, iy, tid);
}

// ---------- iy-DFT of A + channel mix -> F (pre-scaled)  (R2-proven, verbatim)
__global__ __launch_bounds__(256, 4) void k_cm(const float* __restrict__ A,
        const float* __restrict__ w1r, const float* __restrict__ w1i,
        const float* __restrict__ w2r, const float* __restrict__ w2i,
        float* __restrict__ F, int l)
{
    __shared__ float red[4][DV][7][2];       // pad 7: 2-way max = free
    __shared__ float FinS[DV][6][2];
    int blk = blockIdx.x;
    int mg = blk & 3;
    int bk = blk >> 2;                       // b*MM + ky
    int b  = bk / MM;
    int ky = bk - b * MM;
    int tid = threadIdx.x;
    int c = tid & 31, ch = tid >> 5;
    int iy0 = ch * 32;

    const float2* Ap = (const float2*)(A) + ((size_t)(b * SS) * MM + ky) * DV + c;

    float fr[6], fi[6], pc[6], ps[6], sc[6], ssn[6];
    #pragma unroll
    for (int k = 0; k < 6; ++k) {
        int m = mg * 6 + k;
        int f = (m < MM) ? m : (232 + m);    // 244..255 for m >= 12
        float s, cc;
        sincosf(TWO_PI_N * (float)f, &s, &cc);
        sc[k] = cc; ssn[k] = s;
        sincosf(TWO_PI_N * (float)((f * iy0) & 255), &s, &cc);
        pc[k] = cc; ps[k] = s;
        fr[k] = fi[k] = 0.f;
    }
    #pragma unroll 4
    for (int i = 0; i < 32; ++i) {
        float2 a = Ap[(size_t)(iy0 + i) * (MM * DV)];
        #pragma unroll
        for (int k = 0; k < 6; ++k) {
            fr[k] += a.x * pc[k] + a.y * ps[k];   // A * e^{-i th}
            fi[k] += a.y * pc[k] - a.x * ps[k];
            float np = pc[k] * sc[k] - ps[k] * ssn[k];
            float nq = pc[k] * ssn[k] + ps[k] * sc[k];
            pc[k] = np; ps[k] = nq;
        }
    }
    #pragma unroll
    for (int k = 0; k < 6; ++k) {
        fr[k] += __shfl_xor(fr[k], 32, 64);
        fi[k] += __shfl_xor(fi[k], 32, 64);
    }
    int wv = tid >> 6;
    if ((tid & 63) < 32) {
        #pragma unroll
        for (int k = 0; k < 6; ++k) {
            red[wv][c][k][0] = fr[k];
            red[wv][c][k][1] = fi[k];
        }
    }
    __syncthreads();
    if (tid < 192) {
        int cc = tid & 31, k2 = tid >> 5;
        float sr = 0.f, si = 0.f;
        #pragma unroll
        for (int w = 0; w < 4; ++w) {
            sr += red[w][cc][k2][0];
            si += red[w][cc][k2][1];
        }
        FinS[cc][k2][0] = sr; FinS[cc][k2][1] = si;
    }
    __syncthreads();

    int c2 = tid >> 3, ch2 = tid & 7;
    if (ch2 < 6) {
        int o = c2;
        int m = mg * 6 + ch2;
        const float* Wr; const float* Wi; int xm;
        if (m < MM) { Wr = w1r; Wi = w1i; xm = m; }
        else        { Wr = w2r; Wi = w2i; xm = m - MM; }
        float scale = ((ky == 0) ? 1.0f : 2.0f) * (1.0f / 65536.0f);
        float orr = 0.f, oii = 0.f;
        #pragma unroll 4
        for (int i = 0; i < DV; ++i) {
            float gr = FinS[i][ch2][0], gi = FinS[i][ch2][1];
            size_t wi = ((size_t)(l * DV + i) * DV + o) * (MM * MM) + xm * MM + ky;
            float wr = Wr[wi], wim = Wi[wi];
            orr += gr * wr - gi * wim;
            oii += gr * wim + gi * wr;
        }
        size_t off = (((size_t)bk * MK + m) * DV + o) * 2;   // [ky][m][co]
        F[off] = orr * scale; F[off + 1] = oii * scale;
    }
}

// -------------------- inverse iy-DFT: F -> g  (R2-proven, verbatim)
__global__ __launch_bounds__(384) void k_inv1(const float* __restrict__ F,
        float* __restrict__ g)
{
    __shared__ float itw[MK * 2];
    int tid = threadIdx.x;
    int b = blockIdx.x >> 8, iy = blockIdx.x & 255;
    if (tid < MK) {
        int f = (tid < MM) ? tid : (232 + tid);
        float ang = TWO_PI_N * (float)((f * iy) & 255);
        float s, c; sincosf(ang, &s, &c);
        itw[2 * tid] = c; itw[2 * tid + 1] = s;
    }
    __syncthreads();

    int ky = tid >> 5, co = tid & 31;
    const float* Fp = F + ((size_t)(b * MM + ky) * MK) * (DV * 2) + 2 * co;
    float gr = 0.f, gi = 0.f;
    #pragma unroll
    for (int m = 0; m < MK; ++m) {
        float2 fv = *(const float2*)(Fp + (size_t)m * (DV * 2));  // coalesced
        float ic = itw[2 * m], is = itw[2 * m + 1];
        gr += fv.x * ic - fv.y * is;
        gi += fv.x * is + fv.y * ic;
    }
    size_t o = (((size_t)(b * SS + iy)) * MM + ky) * (DV * 2) + 2 * co;
    g[o] = gr; g[o + 1] = gi;
}

// ----------------- FINAL-layer pointwise (R2-proven, verbatim); g via s_loads.
template<int FINAL>
__global__ __launch_bounds__(256, 4) void k_pt(float* __restrict__ h,
        const float* __restrict__ g, const float* __restrict__ wT,
        const float* __restrict__ ws_b, const float* __restrict__ tw2,
        const float* __restrict__ q_w, const float* __restrict__ q_b,
        float* __restrict__ out, int l)
{
    int tid = threadIdx.x;
    int lane = tid & 63;
    int w = __builtin_amdgcn_readfirstlane(tid >> 6);
    int b  = blockIdx.x >> 7;
    int iy = ((blockIdx.x & 127) << 1) + (w >> 1);
    int j0 = ((w & 1) << 7) + (lane << 1);

    float* hb = h + ((size_t)b * DV * SS + iy) * SS + j0;
    const float* wt  = wT + (size_t)l * DV * DV;     // [ci][co], uniform
    const float* wsb = ws_b + (size_t)l * DV;

    float2 acc[DV];
    #pragma unroll
    for (int co = 0; co < DV; ++co) {
        float bv = wsb[co];
        acc[co].x = bv; acc[co].y = bv;
    }

    #pragma unroll 4
    for (int ci = 0; ci < DV; ++ci) {
        float2 hv = *(const float2*)(hb + (size_t)ci * SS * SS);
        const float* wc = wt + ci * DV;              // 32 contiguous s_loads
        #pragma unroll
        for (int co = 0; co < DV; ++co) {
            float wv = wc[co];
            acc[co].x += wv * hv.x; acc[co].y += wv * hv.y;
        }
    }

    const float* gp = g + ((size_t)(b * SS + iy)) * (MM * DV * 2);  // uniform
    #pragma unroll 2
    for (int ky = 0; ky < MM; ++ky) {
        float4 t4 = *(const float4*)(tw2 + ((size_t)ky * SS + j0) * 2);
        const float* Gk = gp + ky * (DV * 2);        // 64 contiguous s_loads
        #pragma unroll
        for (int co = 0; co < DV; ++co) {
            float gr = Gk[2 * co], gi = Gk[2 * co + 1];
            acc[co].x += gr * t4.x - gi * t4.y;
            acc[co].y += gr * t4.z - gi * t4.w;
        }
    }

    if (FINAL) {
        float qb = q_b[0];
        float2 o2; o2.x = qb; o2.y = qb;
        #pragma unroll
        for (int co = 0; co < DV; ++co) {
            float qv = q_w[co];
            o2.x += qv * acc[co].x; o2.y += qv * acc[co].y;
        }
        *(float2*)(out + ((size_t)(b * SS + iy)) * SS + j0) = o2;
    } else {
        #pragma unroll
        for (int co = 0; co < DV; ++co) {
            float2 v;
            v.x = fmaxf(acc[co].x, 0.f); v.y = fmaxf(acc[co].y, 0.f);
            *(float2*)(hb + (size_t)co * SS * SS) = v;
        }
    }
}

extern "C" void kernel_launch(void* const* d_in, const int* in_sizes, int n_in,
                              void* d_out, int out_size, void* d_ws, size_t ws_size,
                              hipStream_t stream)
{
    const float* x    = (const float*)d_in[0];
    const float* p_w  = (const float*)d_in[1];
    const float* p_b  = (const float*)d_in[2];
    const float* ws_w = (const float*)d_in[3];
    const float* ws_b = (const float*)d_in[4];
    const float* w1r  = (const float*)d_in[5];
    const float* w1i  = (const float*)d_in[6];
    const float* w2r  = (const float*)d_in[7];
    const float* w2i  = (const float*)d_in[8];
    const float* q_w  = (const float*)d_in[9];
    const float* q_b  = (const float*)d_in[10];
    float* out = (float*)d_out;

    float* h   = (float*)d_ws;
    float* A   = h   + (size_t)NB * DV * SS * SS;
    float* F   = A   + (size_t)NB * SS * MM * DV * 2;
    float* g   = F   + (size_t)NB * MM * MK * DV * 2;
    float* twT = g   + (size_t)NB * SS * MM * DV * 2;
    float* wT  = twT + (size_t)SS * MM * 2;
    float* tw2 = wT  + (size_t)LL * DV * DV;

    dim3 blk(256);
    k_prep<<<1, blk, 0, stream>>>(ws_w, twT, wT, tw2);
    // lifting + row-DFT for layer 0's A, fused
    k_liftdft<<<NB * SS, blk, 0, stream>>>(x, p_w, p_b, h, twT, A);
    for (int l = 0; l < LL; ++l) {
        k_cm<<<NB * MM * 4, blk, 0, stream>>>(A, w1r, w1i, w2r, w2i, F, l);
        k_inv1<<<NB * SS, dim3(384), 0, stream>>>(F, g);
        if (l < LL - 1)
            k_ptdft<<<NB * SS, blk, 0, stream>>>(h, g, wT, ws_b, tw2, twT, A, l);
        else
            k_pt<1><<<NB * 128, blk, 0, stream>>>(h, g, wT, ws_b, tw2,
                                                  q_w, q_b, out, l);
    }
}